// Round 10
// baseline (206.747 us; speedup 1.0000x reference)
//
#include <hip/hip_runtime.h>

#define IN_DIM 128
#define OUT_DIM 64
#define ALPHA 0.2f
#define SROWS 64               // rows staged per block iteration
#define LROW 132               // bf16 per LDS row: 264B -> fr-lanes on distinct banks

typedef __attribute__((ext_vector_type(8))) short short8v;     // 8 bf16 (4 VGPRs)
typedef __attribute__((ext_vector_type(4))) float f32x4;       // MFMA acc
typedef __attribute__((ext_vector_type(4))) unsigned int u32x4;

__device__ __forceinline__ unsigned short bf16rne(float x) {
    union { float f; unsigned u; } c; c.f = x;
    const unsigned u = c.u;
    return (unsigned short)((u + 0x7fffu + ((u >> 16) & 1u)) >> 16);
}

// ---------------------------------------------------------------------------
// Kernel 1: M_b = P_b @ W_slice_b -> f32 M[3][128][64] and bf16 Mt[3][64][128]
// ---------------------------------------------------------------------------
__global__ __launch_bounds__(256) void compute_M_kernel(
    const float* __restrict__ P_company,
    const float* __restrict__ P_person,
    const float* __restrict__ W_PCC,
    float* __restrict__ M,              // [3][128][64] f32 (fallback path)
    unsigned short* __restrict__ Mt)    // [3][64][128] bf16 (transposed)
{
    const int mb = blockIdx.x >> 4;     // which matrix (0,1,2)
    const int chunk = blockIdx.x & 15;
    const float* __restrict__ P = (mb == 2) ? P_person : P_company;
    const float* __restrict__ Wb = W_PCC + mb * OUT_DIM * OUT_DIM;
    float* __restrict__ Mb = M + mb * IN_DIM * OUT_DIM;
    const int base = chunk * 512;
    for (int idx = base + threadIdx.x; idx < base + 512; idx += 256) {
        const int r = idx >> 6;   // k index 0..127
        const int c = idx & 63;   // col 0..63
        float acc = 0.f;
#pragma unroll
        for (int k = 0; k < OUT_DIM; ++k)
            acc = fmaf(P[r * OUT_DIM + k], Wb[k * OUT_DIM + c], acc);
        Mb[idx] = acc;
        Mt[(mb * OUT_DIM + c) * IN_DIM + r] = bf16rne(acc);
    }
}

// ---------------------------------------------------------------------------
// Kernel 2: table GEMM via MFMA.  Persistent blocks + cooperative LDS staging.
// Block grid-strides over 64-row super-tiles of feats; stages them once
// (coalesced float4 reads, f32->bf16 convert at stage) into padded LDS.
// B/M-fragments (one matrix per wave) loaded from global ONCE per block
// lifetime (64 VGPRs).  Operand-swapped MFMA (R9):
//   a[4h+j] = M^T[c0i*16 + fr][k0 + 16h + fq*4 + j]   (mfrag, A-operand)
//   b[4h+j] = feats[row][k0 + 16h + fq*4 + j]          (xfrag from LDS)
//   D[(fq*4+j)][fr] -> lane stores table[row0+fr][c0i*16 + fq*4 .. +3]
// taxPayer blocks: wave w -> table (w&1), rows (w>>1)*32 + {0..31} (2 tiles);
// each staged row is consumed by BOTH tables from LDS -> A-stream read once.
// person blocks: wave w -> rows w*16 (1 tile).
// ---------------------------------------------------------------------------
__global__ __launch_bounds__(256) void tables_kernel(
    const float* __restrict__ T, int n_c,
    const float* __restrict__ Pp, int n_p,
    const unsigned short* __restrict__ Mt,   // [3][64][128]
    unsigned short* __restrict__ g0,         // [2][n_c][64] (g0 then g1)
    unsigned short* __restrict__ g2,         // [n_p][64]
    int gsplit)
{
    __shared__ unsigned short xs[SROWS][LROW];  // 16.9 KB
    const int w    = threadIdx.x >> 6;
    const int lane = threadIdx.x & 63;
    const int fr   = lane & 15;
    const int fq   = lane >> 4;

    const bool isC = (int)blockIdx.x < gsplit;
    const float* __restrict__ feats = isC ? T : Pp;
    const int nrows = isC ? n_c : n_p;
    const int bid   = isC ? (int)blockIdx.x : (int)blockIdx.x - gsplit;
    const int nb    = isC ? gsplit : (int)gridDim.x - gsplit;
    const int table = isC ? (w & 1) : 2;
    unsigned short* __restrict__ outp =
        isC ? g0 + (size_t)(w & 1) * n_c * OUT_DIM : g2;
    const unsigned short* __restrict__ Mtb = Mt + (size_t)table * OUT_DIM * IN_DIM;

    // preload M fragments (A-operand): 4(k0) x 4(c0) x 8 bf16 = 64 VGPRs, once
    union FragU { short8v v; uint2 q[2]; };
    short8v mfrag[4][4];
#pragma unroll
    for (int k0i = 0; k0i < 4; ++k0i)
#pragma unroll
        for (int c0i = 0; c0i < 4; ++c0i) {
            const unsigned short* p =
                Mtb + ((size_t)(c0i * 16 + fr)) * IN_DIM + k0i * 32 + fq * 4;
            FragU f;
            f.q[0] = *(const uint2*)(p);
            f.q[1] = *(const uint2*)(p + 16);
            mfrag[k0i][c0i] = f.v;
        }

    const int nsup = (nrows + SROWS - 1) / SROWS;
    for (int sup = bid; sup < nsup; sup += nb) {
        const long long row0 = (long long)sup * SROWS;
        __syncthreads();  // previous iteration's LDS reads complete
        // stage 64 rows: coalesced float4 reads, bf16 convert, 8B LDS writes
#pragma unroll
        for (int it = 0; it < (SROWS * (IN_DIM / 4)) / 256; ++it) {
            const int i  = it * 256 + threadIdx.x;
            const int r  = i >> 5;       // row 0..63
            const int c4 = i & 31;       // 16B chunk 0..31
            long long gr = row0 + r;
            if (gr >= nrows) gr = nrows - 1;
            const float4 v = *(const float4*)(feats + gr * IN_DIM + c4 * 4);
            union { unsigned short s[4]; uint2 q; } b;
            b.s[0] = bf16rne(v.x); b.s[1] = bf16rne(v.y);
            b.s[2] = bf16rne(v.z); b.s[3] = bf16rne(v.w);
            *(uint2*)&xs[r][c4 * 4] = b.q;
        }
        __syncthreads();

        const int nt = isC ? 2 : 1;
#pragma unroll
        for (int ti = 0; ti < 2; ++ti) {
            if (ti >= nt) break;
            const int lr = isC ? ((w >> 1) * 32 + ti * 16) : (w * 16);
            // xfrag from LDS (B-operand)
            short8v xfrag[4];
#pragma unroll
            for (int k0i = 0; k0i < 4; ++k0i) {
                FragU af;
                af.q[0] = *(const uint2*)&xs[lr + fr][k0i * 32 + fq * 4];
                af.q[1] = *(const uint2*)&xs[lr + fr][k0i * 32 + 16 + fq * 4];
                xfrag[k0i] = af.v;
            }

            f32x4 acc[4];
#pragma unroll
            for (int c0i = 0; c0i < 4; ++c0i) acc[c0i] = (f32x4){0.f, 0.f, 0.f, 0.f};
#pragma unroll
            for (int k0i = 0; k0i < 4; ++k0i)
#pragma unroll
                for (int c0i = 0; c0i < 4; ++c0i)
                    acc[c0i] = __builtin_amdgcn_mfma_f32_16x16x32_bf16(
                        mfrag[k0i][c0i], xfrag[k0i], acc[c0i], 0, 0, 0);

            // packed store: lane -> table[row0+lr+fr][c0i*16 + fq*4 .. +3]
            const long long gr = row0 + lr + fr;
            if (gr < nrows) {
                unsigned short* __restrict__ orow = outp + gr * OUT_DIM + fq * 4;
#pragma unroll
                for (int c0i = 0; c0i < 4; ++c0i) {
                    union { unsigned short s[4]; uint2 q; } pk;
#pragma unroll
                    for (int j = 0; j < 4; ++j) pk.s[j] = bf16rne(acc[c0i][j]);
                    *(uint2*)(orow + c0i * 16) = pk.q;
                }
            }
        }
    }
}

// ---------------------------------------------------------------------------
// Kernel 3: gather + add + LeakyReLU.  Tables bf16 [nrows][64].
// 8 lanes/edge (lane loads uint4 = 8 bf16 = 16B; 8x16B = full 128B row),
// 4 edges/thread.  Output stores non-temporal (measured neutral).
// ---------------------------------------------------------------------------
__global__ __launch_bounds__(256) void gather_kernel(
    const int* __restrict__ i0, const int* __restrict__ i1, const int* __restrict__ i2,
    const unsigned short* __restrict__ g0, const unsigned short* __restrict__ g1,
    const unsigned short* __restrict__ g2,
    float* __restrict__ out, long long E)
{
    const long long t = (long long)blockIdx.x * 256 + threadIdx.x;
    const long long grp = t >> 3;      // 8 lanes per group
    const int j = (int)t & 7;          // 8-col sub-block within row
    const long long e0 = grp * 4;
    if (e0 >= E) return;

    long long e[4];
    bool live[4];
#pragma unroll
    for (int k = 0; k < 4; ++k) {
        e[k] = e0 + k;
        live[k] = e[k] < E;
        if (!live[k]) e[k] = E - 1;
    }

    int a0[4], a1[4], a2[4];
#pragma unroll
    for (int k = 0; k < 4; ++k) {
        a0[k] = i0[e[k]];
        a1[k] = i1[e[k]];
        a2[k] = i2[e[k]];
    }

    u32x4 v0[4], v1[4], v2[4];
#pragma unroll
    for (int k = 0; k < 4; ++k) {
        v0[k] = *(const u32x4*)(g0 + (long long)a0[k] * OUT_DIM + j * 8);
        v1[k] = *(const u32x4*)(g1 + (long long)a1[k] * OUT_DIM + j * 8);
        v2[k] = *(const u32x4*)(g2 + (long long)a2[k] * OUT_DIM + j * 8);
    }

#pragma unroll
    for (int k = 0; k < 4; ++k) {
        float s[8];
#pragma unroll
        for (int m = 0; m < 4; ++m) {
            const unsigned u0 = v0[k][m], u1 = v1[k][m], u2 = v2[k][m];
            const float lo = __uint_as_float(u0 << 16)
                           + __uint_as_float(u1 << 16)
                           + __uint_as_float(u2 << 16);
            const float hi = __uint_as_float(u0 & 0xffff0000u)
                           + __uint_as_float(u1 & 0xffff0000u)
                           + __uint_as_float(u2 & 0xffff0000u);
            s[2 * m]     = lo >= 0.f ? lo : ALPHA * lo;
            s[2 * m + 1] = hi >= 0.f ? hi : ALPHA * hi;
        }
        if (live[k]) {
            float* __restrict__ o = out + e[k] * OUT_DIM + j * 8;
            const f32x4 q0 = {s[0], s[1], s[2], s[3]};
            const f32x4 q1 = {s[4], s[5], s[6], s[7]};
            __builtin_nontemporal_store(q0, (f32x4*)(o));
            __builtin_nontemporal_store(q1, (f32x4*)(o + 4));
        }
    }
}

// ---------------------------------------------------------------------------
// Fallback (only if ws too small for tables): direct per-edge compute.
// ---------------------------------------------------------------------------
__global__ __launch_bounds__(256) void fused_fallback_kernel(
    const float* __restrict__ T, const float* __restrict__ Pp,
    const int* __restrict__ i0, const int* __restrict__ i1, const int* __restrict__ i2,
    const float* __restrict__ M, float* __restrict__ out, long long E)
{
    const int wave = threadIdx.x >> 6;
    const int lane = threadIdx.x & 63;
    const long long wavesTotal = (long long)gridDim.x * 4;
    const float* __restrict__ M0 = M;
    const float* __restrict__ M1 = M + IN_DIM * OUT_DIM;
    const float* __restrict__ M2 = M + 2 * IN_DIM * OUT_DIM;
    for (long long e = (long long)blockIdx.x * 4 + wave; e < E; e += wavesTotal) {
        const float* __restrict__ x0 = T + (long long)i0[e] * IN_DIM;
        const float* __restrict__ x1 = T + (long long)i1[e] * IN_DIM;
        const float* __restrict__ x2 = Pp + (long long)i2[e] * IN_DIM;
        float acc = 0.f;
#pragma unroll 4
        for (int k = 0; k < IN_DIM; ++k) {
            acc = fmaf(x0[k], M0[k * OUT_DIM + lane], acc);
            acc = fmaf(x1[k], M1[k * OUT_DIM + lane], acc);
            acc = fmaf(x2[k], M2[k * OUT_DIM + lane], acc);
        }
        acc = acc >= 0.f ? acc : ALPHA * acc;
        out[e * OUT_DIM + lane] = acc;
    }
}

// ---------------------------------------------------------------------------
extern "C" void kernel_launch(void* const* d_in, const int* in_sizes, int n_in,
                              void* d_out, int out_size, void* d_ws, size_t ws_size,
                              hipStream_t stream) {
    const float* T    = (const float*)d_in[0];  // taxPayer_feats [N_C,128]
    const float* Pp   = (const float*)d_in[1];  // person_feats   [N_P,128]
    // d_in[2] item_feats: unused for PCC
    const int*   i0   = (const int*)d_in[3];
    const int*   i1   = (const int*)d_in[4];
    const int*   i2   = (const int*)d_in[5];
    const float* Pc   = (const float*)d_in[6];  // P_company [128,64]
    const float* Pper = (const float*)d_in[7];  // P_person  [128,64]
    const float* W    = (const float*)d_in[9];  // W_PCC     [192,64]
    float* out = (float*)d_out;

    const int n_c = in_sizes[0] / IN_DIM;
    const int n_p = in_sizes[1] / IN_DIM;
    const long long E = in_sizes[3];

    // ws layout: [M f32 3*128*64][Mt bf16 3*64*128][tables bf16]
    float* M = (float*)d_ws;
    unsigned short* Mt = (unsigned short*)((char*)d_ws + 98304);
    const size_t tblOff = 98304 + 49152;  // 147456, 128B aligned
    const size_t tblBytes = ((size_t)n_c * 2 + (size_t)n_p) * OUT_DIM * sizeof(unsigned short);

    // 1) fused projection matrices (f32 + transposed bf16)
    compute_M_kernel<<<48, 256, 0, stream>>>(Pc, Pper, W, M, Mt);

    if (ws_size >= tblOff + tblBytes) {
        unsigned short* g0 = (unsigned short*)((char*)d_ws + tblOff);  // [n_c][64]
        unsigned short* g1 = g0 + (size_t)n_c * OUT_DIM;               // [n_c][64]
        unsigned short* g2 = g1 + (size_t)n_c * OUT_DIM;               // [n_p][64]

        // 2) both table GEMMs in one dispatch; persistent blocks, LDS-staged
        const int GA = 1024;  // taxPayer blocks (stage once, both tables consume)
        const int GB = 768;   // person blocks
        tables_kernel<<<GA + GB, 256, 0, stream>>>(T, n_c, Pp, n_p, Mt, g0, g2, GA);

        // 3) gather + add + LeakyReLU (8 lanes/edge, 4 edges/thread)
        const long long groups = (E + 3) / 4;
        const long long threads = groups * 8;
        gather_kernel<<<(int)((threads + 255) / 256), 256, 0, stream>>>(
            i0, i1, i2, g0, g1, g2, out, E);
    } else {
        fused_fallback_kernel<<<16384, 256, 0, stream>>>(T, Pp, i0, i1, i2, M, out, E);
    }
}

// Round 11
// 195.458 us; speedup vs baseline: 1.0578x; 1.0578x over previous
//
#include <hip/hip_runtime.h>

#define IN_DIM 128
#define OUT_DIM 64
#define ALPHA 0.2f

typedef __attribute__((ext_vector_type(8))) short short8v;     // 8 bf16 (4 VGPRs)
typedef __attribute__((ext_vector_type(4))) float f32x4;       // MFMA acc
typedef __attribute__((ext_vector_type(4))) unsigned int u32x4;

__device__ __forceinline__ unsigned short bf16rne(float x) {
    union { float f; unsigned u; } c; c.f = x;
    const unsigned u = c.u;
    return (unsigned short)((u + 0x7fffu + ((u >> 16) & 1u)) >> 16);
}

// ---------------------------------------------------------------------------
// Kernel 1: M_b = P_b @ W_slice_b -> f32 M[3][128][64] and bf16 Mt[3][64][128]
// ---------------------------------------------------------------------------
__global__ __launch_bounds__(256) void compute_M_kernel(
    const float* __restrict__ P_company,
    const float* __restrict__ P_person,
    const float* __restrict__ W_PCC,
    float* __restrict__ M,              // [3][128][64] f32 (fallback path)
    unsigned short* __restrict__ Mt)    // [3][64][128] bf16 (transposed)
{
    const int mb = blockIdx.x >> 4;     // which matrix (0,1,2)
    const int chunk = blockIdx.x & 15;
    const float* __restrict__ P = (mb == 2) ? P_person : P_company;
    const float* __restrict__ Wb = W_PCC + mb * OUT_DIM * OUT_DIM;
    float* __restrict__ Mb = M + mb * IN_DIM * OUT_DIM;
    const int base = chunk * 512;
    for (int idx = base + threadIdx.x; idx < base + 512; idx += 256) {
        const int r = idx >> 6;   // k index 0..127
        const int c = idx & 63;   // col 0..63
        float acc = 0.f;
#pragma unroll
        for (int k = 0; k < OUT_DIM; ++k)
            acc = fmaf(P[r * OUT_DIM + k], Wb[k * OUT_DIM + c], acc);
        Mb[idx] = acc;
        Mt[(mb * OUT_DIM + c) * IN_DIM + r] = bf16rne(acc);
    }
}

// ---------------------------------------------------------------------------
// Table GEMM via MFMA, register path (LDS staging lost in every grain).
// Operand-swapped (R9):
//   a[4h+j] = M^T[c0i*16 + fr][k0 + 16h + fq*4 + j]   (mfrag, A-operand)
//   b[4h+j] = feats[row][k0 + 16h + fq*4 + j]          (xfrag)
//   lane stores table[tile*16+fr][c0i*16 + fq*4 .. +3] as one uint2
//
// tablesC: ONE WAVE -> BOTH taxPayer tables. mfrag[2][4][4] = 128 VGPRs,
//   A loaded ONCE per tile (8 float4, dbuf-prefetched), 16 cvt, 32 MFMA,
//   8 packed stores. Halves A VMEM instructions + L2 requests + cvt work
//   vs the wave-pair dup-read scheme. ~250 VGPR -> 2 waves/SIMD.
// tablesP: person table, one wave -> one table (~170 VGPR, 3 waves/SIMD).
// Separate dispatches so each path gets its own register budget.
// ---------------------------------------------------------------------------
union F4 { float4 v; float f[4]; };

__device__ __forceinline__ void load_X(F4* L, const float* __restrict__ feats,
                                       int nrows, int tile, int fr, int fq) {
    long long ar = (long long)tile * 16 + fr;
    if (ar >= nrows) ar = nrows - 1;
    const float* __restrict__ A = feats + ar * IN_DIM;
#pragma unroll
    for (int k0i = 0; k0i < 4; ++k0i) {
        L[k0i * 2 + 0].v = *(const float4*)(A + k0i * 32 + fq * 4);
        L[k0i * 2 + 1].v = *(const float4*)(A + k0i * 32 + 16 + fq * 4);
    }
}

union FragU { short8v v; uint2 q[2]; };
union AF { short8v v; unsigned short u[8]; };

__global__ __launch_bounds__(256, 2) void tablesC_kernel(
    const float* __restrict__ T, int n_c,
    const unsigned short* __restrict__ Mt,   // [2][64][128] (tables 0,1)
    unsigned short* __restrict__ g0,
    unsigned short* __restrict__ g1)
{
    const int w    = threadIdx.x >> 6;
    const int lane = threadIdx.x & 63;
    const int fr   = lane & 15;
    const int fq   = lane >> 4;

    // mfrag for BOTH tables: 2 x 4(k0) x 4(c0) x 8 bf16 = 128 VGPRs
    short8v mfrag[2][4][4];
#pragma unroll
    for (int t = 0; t < 2; ++t)
#pragma unroll
        for (int k0i = 0; k0i < 4; ++k0i)
#pragma unroll
            for (int c0i = 0; c0i < 4; ++c0i) {
                const unsigned short* p = Mt + (size_t)t * OUT_DIM * IN_DIM +
                    ((size_t)(c0i * 16 + fr)) * IN_DIM + k0i * 32 + fq * 4;
                FragU f;
                f.q[0] = *(const uint2*)(p);
                f.q[1] = *(const uint2*)(p + 16);
                mfrag[t][k0i][c0i] = f.v;
            }

    const int ntiles  = (n_c + 15) >> 4;
    const int wstride = gridDim.x * 4;
    int tile = (int)blockIdx.x * 4 + w;
    if (tile >= ntiles) return;

    F4 La[8];
    load_X(La, T, n_c, tile, fr, fq);

    for (; tile < ntiles; tile += wstride) {
        const int next = tile + wstride;
        F4 Lb[8];
        if (next < ntiles) load_X(Lb, T, n_c, next, fr, fq);  // prefetch

        short8v xfrag[4];
#pragma unroll
        for (int k0i = 0; k0i < 4; ++k0i) {
            AF af;
#pragma unroll
            for (int j = 0; j < 4; ++j) {
                af.u[j]     = bf16rne(La[k0i * 2 + 0].f[j]);
                af.u[4 + j] = bf16rne(La[k0i * 2 + 1].f[j]);
            }
            xfrag[k0i] = af.v;
        }

        f32x4 acc0[4], acc1[4];
#pragma unroll
        for (int c0i = 0; c0i < 4; ++c0i) {
            acc0[c0i] = (f32x4){0.f, 0.f, 0.f, 0.f};
            acc1[c0i] = (f32x4){0.f, 0.f, 0.f, 0.f};
        }
#pragma unroll
        for (int k0i = 0; k0i < 4; ++k0i)
#pragma unroll
            for (int c0i = 0; c0i < 4; ++c0i) {
                acc0[c0i] = __builtin_amdgcn_mfma_f32_16x16x32_bf16(
                    mfrag[0][k0i][c0i], xfrag[k0i], acc0[c0i], 0, 0, 0);
                acc1[c0i] = __builtin_amdgcn_mfma_f32_16x16x32_bf16(
                    mfrag[1][k0i][c0i], xfrag[k0i], acc1[c0i], 0, 0, 0);
            }

        const long long gr = (long long)tile * 16 + fr;
        if (gr < n_c) {
            unsigned short* __restrict__ o0 = g0 + gr * OUT_DIM + fq * 4;
            unsigned short* __restrict__ o1 = g1 + gr * OUT_DIM + fq * 4;
#pragma unroll
            for (int c0i = 0; c0i < 4; ++c0i) {
                union { unsigned short s[4]; uint2 q; } p0, p1;
#pragma unroll
                for (int j = 0; j < 4; ++j) {
                    p0.s[j] = bf16rne(acc0[c0i][j]);
                    p1.s[j] = bf16rne(acc1[c0i][j]);
                }
                *(uint2*)(o0 + c0i * 16) = p0.q;
                *(uint2*)(o1 + c0i * 16) = p1.q;
            }
        }

#pragma unroll
        for (int i = 0; i < 8; ++i) La[i] = Lb[i];
    }
}

__global__ __launch_bounds__(256) void tablesP_kernel(
    const float* __restrict__ Pp, int n_p,
    const unsigned short* __restrict__ Mtb,  // [64][128] (table 2)
    unsigned short* __restrict__ g2)
{
    const int w    = threadIdx.x >> 6;
    const int lane = threadIdx.x & 63;
    const int fr   = lane & 15;
    const int fq   = lane >> 4;

    short8v mfrag[4][4];
#pragma unroll
    for (int k0i = 0; k0i < 4; ++k0i)
#pragma unroll
        for (int c0i = 0; c0i < 4; ++c0i) {
            const unsigned short* p =
                Mtb + ((size_t)(c0i * 16 + fr)) * IN_DIM + k0i * 32 + fq * 4;
            FragU f;
            f.q[0] = *(const uint2*)(p);
            f.q[1] = *(const uint2*)(p + 16);
            mfrag[k0i][c0i] = f.v;
        }

    const int ntiles  = (n_p + 15) >> 4;
    const int wstride = gridDim.x * 4;
    int tile = (int)blockIdx.x * 4 + w;
    if (tile >= ntiles) return;

    F4 La[8];
    load_X(La, Pp, n_p, tile, fr, fq);

    for (; tile < ntiles; tile += wstride) {
        const int next = tile + wstride;
        F4 Lb[8];
        if (next < ntiles) load_X(Lb, Pp, n_p, next, fr, fq);  // prefetch

        short8v xfrag[4];
#pragma unroll
        for (int k0i = 0; k0i < 4; ++k0i) {
            AF af;
#pragma unroll
            for (int j = 0; j < 4; ++j) {
                af.u[j]     = bf16rne(La[k0i * 2 + 0].f[j]);
                af.u[4 + j] = bf16rne(La[k0i * 2 + 1].f[j]);
            }
            xfrag[k0i] = af.v;
        }

        f32x4 acc[4];
#pragma unroll
        for (int c0i = 0; c0i < 4; ++c0i) acc[c0i] = (f32x4){0.f, 0.f, 0.f, 0.f};
#pragma unroll
        for (int k0i = 0; k0i < 4; ++k0i)
#pragma unroll
            for (int c0i = 0; c0i < 4; ++c0i)
                acc[c0i] = __builtin_amdgcn_mfma_f32_16x16x32_bf16(
                    mfrag[k0i][c0i], xfrag[k0i], acc[c0i], 0, 0, 0);

        const long long gr = (long long)tile * 16 + fr;
        if (gr < n_p) {
            unsigned short* __restrict__ orow = g2 + gr * OUT_DIM + fq * 4;
#pragma unroll
            for (int c0i = 0; c0i < 4; ++c0i) {
                union { unsigned short s[4]; uint2 q; } pk;
#pragma unroll
                for (int j = 0; j < 4; ++j) pk.s[j] = bf16rne(acc[c0i][j]);
                *(uint2*)(orow + c0i * 16) = pk.q;
            }
        }

#pragma unroll
        for (int i = 0; i < 8; ++i) La[i] = Lb[i];
    }
}

// ---------------------------------------------------------------------------
// Kernel 3: gather + add + LeakyReLU.  Tables bf16 [nrows][64].
// 8 lanes/edge (lane loads uint4 = 8 bf16 = 16B; 8x16B = full 128B row),
// 4 edges/thread.  Output stores non-temporal (measured neutral).
// ---------------------------------------------------------------------------
__global__ __launch_bounds__(256) void gather_kernel(
    const int* __restrict__ i0, const int* __restrict__ i1, const int* __restrict__ i2,
    const unsigned short* __restrict__ g0, const unsigned short* __restrict__ g1,
    const unsigned short* __restrict__ g2,
    float* __restrict__ out, long long E)
{
    const long long t = (long long)blockIdx.x * 256 + threadIdx.x;
    const long long grp = t >> 3;      // 8 lanes per group
    const int j = (int)t & 7;          // 8-col sub-block within row
    const long long e0 = grp * 4;
    if (e0 >= E) return;

    long long e[4];
    bool live[4];
#pragma unroll
    for (int k = 0; k < 4; ++k) {
        e[k] = e0 + k;
        live[k] = e[k] < E;
        if (!live[k]) e[k] = E - 1;
    }

    int a0[4], a1[4], a2[4];
#pragma unroll
    for (int k = 0; k < 4; ++k) {
        a0[k] = i0[e[k]];
        a1[k] = i1[e[k]];
        a2[k] = i2[e[k]];
    }

    u32x4 v0[4], v1[4], v2[4];
#pragma unroll
    for (int k = 0; k < 4; ++k) {
        v0[k] = *(const u32x4*)(g0 + (long long)a0[k] * OUT_DIM + j * 8);
        v1[k] = *(const u32x4*)(g1 + (long long)a1[k] * OUT_DIM + j * 8);
        v2[k] = *(const u32x4*)(g2 + (long long)a2[k] * OUT_DIM + j * 8);
    }

#pragma unroll
    for (int k = 0; k < 4; ++k) {
        float s[8];
#pragma unroll
        for (int m = 0; m < 4; ++m) {
            const unsigned u0 = v0[k][m], u1 = v1[k][m], u2 = v2[k][m];
            const float lo = __uint_as_float(u0 << 16)
                           + __uint_as_float(u1 << 16)
                           + __uint_as_float(u2 << 16);
            const float hi = __uint_as_float(u0 & 0xffff0000u)
                           + __uint_as_float(u1 & 0xffff0000u)
                           + __uint_as_float(u2 & 0xffff0000u);
            s[2 * m]     = lo >= 0.f ? lo : ALPHA * lo;
            s[2 * m + 1] = hi >= 0.f ? hi : ALPHA * hi;
        }
        if (live[k]) {
            float* __restrict__ o = out + e[k] * OUT_DIM + j * 8;
            const f32x4 q0 = {s[0], s[1], s[2], s[3]};
            const f32x4 q1 = {s[4], s[5], s[6], s[7]};
            __builtin_nontemporal_store(q0, (f32x4*)(o));
            __builtin_nontemporal_store(q1, (f32x4*)(o + 4));
        }
    }
}

// ---------------------------------------------------------------------------
// Fallback (only if ws too small for tables): direct per-edge compute.
// ---------------------------------------------------------------------------
__global__ __launch_bounds__(256) void fused_fallback_kernel(
    const float* __restrict__ T, const float* __restrict__ Pp,
    const int* __restrict__ i0, const int* __restrict__ i1, const int* __restrict__ i2,
    const float* __restrict__ M, float* __restrict__ out, long long E)
{
    const int wave = threadIdx.x >> 6;
    const int lane = threadIdx.x & 63;
    const long long wavesTotal = (long long)gridDim.x * 4;
    const float* __restrict__ M0 = M;
    const float* __restrict__ M1 = M + IN_DIM * OUT_DIM;
    const float* __restrict__ M2 = M + 2 * IN_DIM * OUT_DIM;
    for (long long e = (long long)blockIdx.x * 4 + wave; e < E; e += wavesTotal) {
        const float* __restrict__ x0 = T + (long long)i0[e] * IN_DIM;
        const float* __restrict__ x1 = T + (long long)i1[e] * IN_DIM;
        const float* __restrict__ x2 = Pp + (long long)i2[e] * IN_DIM;
        float acc = 0.f;
#pragma unroll 4
        for (int k = 0; k < IN_DIM; ++k) {
            acc = fmaf(x0[k], M0[k * OUT_DIM + lane], acc);
            acc = fmaf(x1[k], M1[k * OUT_DIM + lane], acc);
            acc = fmaf(x2[k], M2[k * OUT_DIM + lane], acc);
        }
        acc = acc >= 0.f ? acc : ALPHA * acc;
        out[e * OUT_DIM + lane] = acc;
    }
}

// ---------------------------------------------------------------------------
extern "C" void kernel_launch(void* const* d_in, const int* in_sizes, int n_in,
                              void* d_out, int out_size, void* d_ws, size_t ws_size,
                              hipStream_t stream) {
    const float* T    = (const float*)d_in[0];  // taxPayer_feats [N_C,128]
    const float* Pp   = (const float*)d_in[1];  // person_feats   [N_P,128]
    // d_in[2] item_feats: unused for PCC
    const int*   i0   = (const int*)d_in[3];
    const int*   i1   = (const int*)d_in[4];
    const int*   i2   = (const int*)d_in[5];
    const float* Pc   = (const float*)d_in[6];  // P_company [128,64]
    const float* Pper = (const float*)d_in[7];  // P_person  [128,64]
    const float* W    = (const float*)d_in[9];  // W_PCC     [192,64]
    float* out = (float*)d_out;

    const int n_c = in_sizes[0] / IN_DIM;
    const int n_p = in_sizes[1] / IN_DIM;
    const long long E = in_sizes[3];

    // ws layout: [M f32 3*128*64][Mt bf16 3*64*128][tables bf16]
    float* M = (float*)d_ws;
    unsigned short* Mt = (unsigned short*)((char*)d_ws + 98304);
    const size_t tblOff = 98304 + 49152;  // 147456, 128B aligned
    const size_t tblBytes = ((size_t)n_c * 2 + (size_t)n_p) * OUT_DIM * sizeof(unsigned short);

    // 1) fused projection matrices (f32 + transposed bf16)
    compute_M_kernel<<<48, 256, 0, stream>>>(Pc, Pper, W, M, Mt);

    if (ws_size >= tblOff + tblBytes) {
        unsigned short* g0 = (unsigned short*)((char*)d_ws + tblOff);  // [n_c][64]
        unsigned short* g1 = g0 + (size_t)n_c * OUT_DIM;               // [n_c][64]
        unsigned short* g2 = g1 + (size_t)n_c * OUT_DIM;               // [n_p][64]

        // 2) table GEMMs: taxPayer (one wave -> both tables), then person
        tablesC_kernel<<<1024, 256, 0, stream>>>(T, n_c, Mt, g0, g1);
        tablesP_kernel<<<512, 256, 0, stream>>>(
            Pp, n_p, Mt + (size_t)2 * OUT_DIM * IN_DIM, g2);

        // 3) gather + add + LeakyReLU (8 lanes/edge, 4 edges/thread)
        const long long groups = (E + 3) / 4;
        const long long threads = groups * 8;
        gather_kernel<<<(int)((threads + 255) / 256), 256, 0, stream>>>(
            i0, i1, i2, g0, g1, g2, out, E);
    } else {
        fused_fallback_kernel<<<16384, 256, 0, stream>>>(T, Pp, i0, i1, i2, M, out, E);
    }
}

// Round 12
// 189.828 us; speedup vs baseline: 1.0891x; 1.0297x over previous
//
#include <hip/hip_runtime.h>

#define IN_DIM 128
#define OUT_DIM 64
#define ALPHA 0.2f

typedef __attribute__((ext_vector_type(8))) short short8v;     // 8 bf16 (4 VGPRs)
typedef __attribute__((ext_vector_type(4))) float f32x4;       // MFMA acc
typedef __attribute__((ext_vector_type(4))) unsigned int u32x4;

__device__ __forceinline__ unsigned short bf16rne(float x) {
    union { float f; unsigned u; } c; c.f = x;
    const unsigned u = c.u;
    return (unsigned short)((u + 0x7fffu + ((u >> 16) & 1u)) >> 16);
}

// ---------------------------------------------------------------------------
// Kernel 1: M_b = P_b @ W_slice_b -> f32 M[3][128][64] and bf16 Mt[3][64][128]
// ---------------------------------------------------------------------------
__global__ __launch_bounds__(256) void compute_M_kernel(
    const float* __restrict__ P_company,
    const float* __restrict__ P_person,
    const float* __restrict__ W_PCC,
    float* __restrict__ M,              // [3][128][64] f32 (fallback path)
    unsigned short* __restrict__ Mt)    // [3][64][128] bf16 (transposed)
{
    const int mb = blockIdx.x >> 4;     // which matrix (0,1,2)
    const int chunk = blockIdx.x & 15;
    const float* __restrict__ P = (mb == 2) ? P_person : P_company;
    const float* __restrict__ Wb = W_PCC + mb * OUT_DIM * OUT_DIM;
    float* __restrict__ Mb = M + mb * IN_DIM * OUT_DIM;
    const int base = chunk * 512;
    for (int idx = base + threadIdx.x; idx < base + 512; idx += 256) {
        const int r = idx >> 6;   // k index 0..127
        const int c = idx & 63;   // col 0..63
        float acc = 0.f;
#pragma unroll
        for (int k = 0; k < OUT_DIM; ++k)
            acc = fmaf(P[r * OUT_DIM + k], Wb[k * OUT_DIM + c], acc);
        Mb[idx] = acc;
        Mt[(mb * OUT_DIM + c) * IN_DIM + r] = bf16rne(acc);
    }
}

// ---------------------------------------------------------------------------
// Kernel 2: table GEMM via MFMA, merged dispatch (best-measured R8 config).
// Each wave computes ONE table's 64 cols for a 16-row tile; B (one matrix,
// bf16) lives in 64 VGPRs, preloaded once per wave. A (f32) is double-buffered
// in registers: next tile's 8 float4 loads issue before this tile's MFMAs.
// taxPayer blocks: waves {0,1} share tile (table 0/1), waves {2,3} next tile
// -> A cache lines fetched once from HBM, dup wave read hits L2 (cached loads
// on purpose -- NT here was R6's regression).
// Fragment maps (16x16x32 bf16):
//   a[4h+j] = A[l&15][k0 + 16h + (l>>4)*4 + j]
//   b[4h+j] = M[k0 + 16h + (l>>4)*4 + j][c0 + (l&15)]
//   D[(l>>4)*4 + j][c0 + (l&15)] = acc[j]
// ---------------------------------------------------------------------------
union F4 { float4 v; float f[4]; };

__device__ __forceinline__ void load_A(F4* L, const float* __restrict__ feats,
                                       int nrows, int tile, int fr, int fq) {
    long long ar = (long long)tile * 16 + fr;
    if (ar >= nrows) ar = nrows - 1;
    const float* __restrict__ A = feats + ar * IN_DIM;
#pragma unroll
    for (int k0i = 0; k0i < 4; ++k0i) {
        L[k0i * 2 + 0].v = *(const float4*)(A + k0i * 32 + fq * 4);
        L[k0i * 2 + 1].v = *(const float4*)(A + k0i * 32 + 16 + fq * 4);
    }
}

__device__ __forceinline__ void table_body(
    const float* __restrict__ feats, int nrows,
    const unsigned short* __restrict__ Mtb,  // one matrix [64][128] bf16
    unsigned short* __restrict__ out,        // one table [nrows][64] bf16
    int tile0, int tstride)
{
    const int lane = threadIdx.x & 63;
    const int fr   = lane & 15;   // A-row / B,D-col index
    const int fq   = lane >> 4;   // k-subgroup / D-row-group

    // preload B fragments: 4(k0) x 4(c0) x 8 bf16 = 64 VGPRs
    union FragU { short8v v; uint2 q[2]; };
    short8v bfrag[4][4];
#pragma unroll
    for (int k0i = 0; k0i < 4; ++k0i)
#pragma unroll
        for (int c0i = 0; c0i < 4; ++c0i) {
            const unsigned short* p =
                Mtb + ((size_t)(c0i * 16 + fr)) * IN_DIM + k0i * 32 + fq * 4;
            FragU f;
            f.q[0] = *(const uint2*)(p);
            f.q[1] = *(const uint2*)(p + 16);
            bfrag[k0i][c0i] = f.v;
        }

    const int ntiles = (nrows + 15) >> 4;
    union AF { short8v v; unsigned short u[8]; };

    int tile = tile0;
    if (tile >= ntiles) return;
    F4 La[8];
    load_A(La, feats, nrows, tile, fr, fq);

    for (; tile < ntiles; tile += tstride) {
        const int next = tile + tstride;
        F4 Lb[8];
        if (next < ntiles) load_A(Lb, feats, nrows, next, fr, fq);  // prefetch

        short8v afrag[4];
#pragma unroll
        for (int k0i = 0; k0i < 4; ++k0i) {
            AF af;
#pragma unroll
            for (int j = 0; j < 4; ++j) {
                af.u[j]     = bf16rne(La[k0i * 2 + 0].f[j]);
                af.u[4 + j] = bf16rne(La[k0i * 2 + 1].f[j]);
            }
            afrag[k0i] = af.v;
        }

        f32x4 acc[4];
#pragma unroll
        for (int c0i = 0; c0i < 4; ++c0i) acc[c0i] = (f32x4){0.f, 0.f, 0.f, 0.f};
#pragma unroll
        for (int k0i = 0; k0i < 4; ++k0i)
#pragma unroll
            for (int c0i = 0; c0i < 4; ++c0i)
                acc[c0i] = __builtin_amdgcn_mfma_f32_16x16x32_bf16(
                    afrag[k0i], bfrag[k0i][c0i], acc[c0i], 0, 0, 0);

        const long long row0 = (long long)tile * 16;
        // table stores stay CACHED: gather re-reads them from L2/L3
#pragma unroll
        for (int c0i = 0; c0i < 4; ++c0i)
#pragma unroll
            for (int j = 0; j < 4; ++j) {
                const long long rg = row0 + fq * 4 + j;
                if (rg < nrows)
                    out[rg * OUT_DIM + c0i * 16 + fr] = bf16rne(acc[c0i][j]);
            }

#pragma unroll
        for (int i = 0; i < 8; ++i) La[i] = Lb[i];
    }
}

__global__ __launch_bounds__(256) void tables_kernel(
    const float* __restrict__ T, int n_c,
    const float* __restrict__ Pp, int n_p,
    const unsigned short* __restrict__ Mt,   // [3][64][128]
    unsigned short* __restrict__ g0,         // [2][n_c][64] (g0 then g1)
    unsigned short* __restrict__ g2,         // [n_p][64]
    int gsplit)
{
    const int w = threadIdx.x >> 6;
    if ((int)blockIdx.x < gsplit) {
        // taxPayer: waves {0,1} -> tile 2*bid, tables {0,1}; waves {2,3} -> tile 2*bid+1
        const int table = w & 1;
        const int tile0 = (int)blockIdx.x * 2 + (w >> 1);
        table_body(T, n_c,
                   Mt + (size_t)table * OUT_DIM * IN_DIM,
                   g0 + (size_t)table * n_c * OUT_DIM,
                   tile0, gsplit * 2);
    } else {
        const int bid = (int)blockIdx.x - gsplit;
        const int nb  = (int)gridDim.x - gsplit;
        table_body(Pp, n_p,
                   Mt + (size_t)2 * OUT_DIM * IN_DIM,
                   g2, bid * 4 + w, nb * 4);
    }
}

// ---------------------------------------------------------------------------
// Kernel 3: gather + add + LeakyReLU.  Tables bf16 [nrows][64].
// 8 lanes/edge (lane loads uint4 = 8 bf16 = 16B; 8x16B = full 128B row),
// 4 edges/thread. Output stores non-temporal (measured neutral).
// ---------------------------------------------------------------------------
__global__ __launch_bounds__(256) void gather_kernel(
    const int* __restrict__ i0, const int* __restrict__ i1, const int* __restrict__ i2,
    const unsigned short* __restrict__ g0, const unsigned short* __restrict__ g1,
    const unsigned short* __restrict__ g2,
    float* __restrict__ out, long long E)
{
    const long long t = (long long)blockIdx.x * 256 + threadIdx.x;
    const long long grp = t >> 3;      // 8 lanes per group
    const int j = (int)t & 7;          // 8-col sub-block within row
    const long long e0 = grp * 4;
    if (e0 >= E) return;

    long long e[4];
    bool live[4];
#pragma unroll
    for (int k = 0; k < 4; ++k) {
        e[k] = e0 + k;
        live[k] = e[k] < E;
        if (!live[k]) e[k] = E - 1;
    }

    int a0[4], a1[4], a2[4];
#pragma unroll
    for (int k = 0; k < 4; ++k) {
        a0[k] = i0[e[k]];
        a1[k] = i1[e[k]];
        a2[k] = i2[e[k]];
    }

    u32x4 v0[4], v1[4], v2[4];
#pragma unroll
    for (int k = 0; k < 4; ++k) {
        v0[k] = *(const u32x4*)(g0 + (long long)a0[k] * OUT_DIM + j * 8);
        v1[k] = *(const u32x4*)(g1 + (long long)a1[k] * OUT_DIM + j * 8);
        v2[k] = *(const u32x4*)(g2 + (long long)a2[k] * OUT_DIM + j * 8);
    }

#pragma unroll
    for (int k = 0; k < 4; ++k) {
        float s[8];
#pragma unroll
        for (int m = 0; m < 4; ++m) {
            const unsigned u0 = v0[k][m], u1 = v1[k][m], u2 = v2[k][m];
            const float lo = __uint_as_float(u0 << 16)
                           + __uint_as_float(u1 << 16)
                           + __uint_as_float(u2 << 16);
            const float hi = __uint_as_float(u0 & 0xffff0000u)
                           + __uint_as_float(u1 & 0xffff0000u)
                           + __uint_as_float(u2 & 0xffff0000u);
            s[2 * m]     = lo >= 0.f ? lo : ALPHA * lo;
            s[2 * m + 1] = hi >= 0.f ? hi : ALPHA * hi;
        }
        if (live[k]) {
            float* __restrict__ o = out + e[k] * OUT_DIM + j * 8;
            const f32x4 q0 = {s[0], s[1], s[2], s[3]};
            const f32x4 q1 = {s[4], s[5], s[6], s[7]};
            __builtin_nontemporal_store(q0, (f32x4*)(o));
            __builtin_nontemporal_store(q1, (f32x4*)(o + 4));
        }
    }
}

// ---------------------------------------------------------------------------
// Fallback (only if ws too small for tables): direct per-edge compute.
// ---------------------------------------------------------------------------
__global__ __launch_bounds__(256) void fused_fallback_kernel(
    const float* __restrict__ T, const float* __restrict__ Pp,
    const int* __restrict__ i0, const int* __restrict__ i1, const int* __restrict__ i2,
    const float* __restrict__ M, float* __restrict__ out, long long E)
{
    const int wave = threadIdx.x >> 6;
    const int lane = threadIdx.x & 63;
    const long long wavesTotal = (long long)gridDim.x * 4;
    const float* __restrict__ M0 = M;
    const float* __restrict__ M1 = M + IN_DIM * OUT_DIM;
    const float* __restrict__ M2 = M + 2 * IN_DIM * OUT_DIM;
    for (long long e = (long long)blockIdx.x * 4 + wave; e < E; e += wavesTotal) {
        const float* __restrict__ x0 = T + (long long)i0[e] * IN_DIM;
        const float* __restrict__ x1 = T + (long long)i1[e] * IN_DIM;
        const float* __restrict__ x2 = Pp + (long long)i2[e] * IN_DIM;
        float acc = 0.f;
#pragma unroll 4
        for (int k = 0; k < IN_DIM; ++k) {
            acc = fmaf(x0[k], M0[k * OUT_DIM + lane], acc);
            acc = fmaf(x1[k], M1[k * OUT_DIM + lane], acc);
            acc = fmaf(x2[k], M2[k * OUT_DIM + lane], acc);
        }
        acc = acc >= 0.f ? acc : ALPHA * acc;
        out[e * OUT_DIM + lane] = acc;
    }
}

// ---------------------------------------------------------------------------
extern "C" void kernel_launch(void* const* d_in, const int* in_sizes, int n_in,
                              void* d_out, int out_size, void* d_ws, size_t ws_size,
                              hipStream_t stream) {
    const float* T    = (const float*)d_in[0];  // taxPayer_feats [N_C,128]
    const float* Pp   = (const float*)d_in[1];  // person_feats   [N_P,128]
    // d_in[2] item_feats: unused for PCC
    const int*   i0   = (const int*)d_in[3];
    const int*   i1   = (const int*)d_in[4];
    const int*   i2   = (const int*)d_in[5];
    const float* Pc   = (const float*)d_in[6];  // P_company [128,64]
    const float* Pper = (const float*)d_in[7];  // P_person  [128,64]
    const float* W    = (const float*)d_in[9];  // W_PCC     [192,64]
    float* out = (float*)d_out;

    const int n_c = in_sizes[0] / IN_DIM;
    const int n_p = in_sizes[1] / IN_DIM;
    const long long E = in_sizes[3];

    // ws layout: [M f32 3*128*64][Mt bf16 3*64*128][tables bf16]
    float* M = (float*)d_ws;
    unsigned short* Mt = (unsigned short*)((char*)d_ws + 98304);
    const size_t tblOff = 98304 + 49152;  // 147456, 128B aligned
    const size_t tblBytes = ((size_t)n_c * 2 + (size_t)n_p) * OUT_DIM * sizeof(unsigned short);

    // 1) fused projection matrices (f32 + transposed bf16)
    compute_M_kernel<<<48, 256, 0, stream>>>(Pc, Pper, W, M, Mt);

    if (ws_size >= tblOff + tblBytes) {
        unsigned short* g0 = (unsigned short*)((char*)d_ws + tblOff);  // [n_c][64]
        unsigned short* g1 = g0 + (size_t)n_c * OUT_DIM;               // [n_c][64]
        unsigned short* g2 = g1 + (size_t)n_c * OUT_DIM;               // [n_p][64]

        // 2) both table GEMMs in one dispatch (overlapped streams)
        const int GA = 1024;  // taxPayer blocks (2 tiles x 2 tables per block)
        const int GB = 512;   // person blocks   (4 tiles per block)
        tables_kernel<<<GA + GB, 256, 0, stream>>>(T, n_c, Pp, n_p, Mt, g0, g2, GA);

        // 3) gather + add + LeakyReLU (8 lanes/edge, 4 edges/thread)
        const long long groups = (E + 3) / 4;
        const long long threads = groups * 8;
        gather_kernel<<<(int)((threads + 255) / 256), 256, 0, stream>>>(
            i0, i1, i2, g0, g1, g2, out, E);
    } else {
        fused_fallback_kernel<<<16384, 256, 0, stream>>>(T, Pp, i0, i1, i2, M, out, E);
    }
}